// Round 7
// baseline (390.720 us; speedup 1.0000x reference)
//
#include <hip/hip_runtime.h>
#include <cstdint>
#include <cstddef>

#define B_ 2048
#define N_ 49
#define H_ 1024
#define A_ 512
#define M_ (B_*N_)   // 100352 = 784*128

typedef __attribute__((ext_vector_type(8))) short short8;
typedef __attribute__((ext_vector_type(4))) float f32x4;
typedef unsigned int u32;

__device__ inline unsigned short f2bf(float f){
  union { float f; unsigned u; } v; v.f = f;
  unsigned r = v.u + 0x7FFFu + ((v.u >> 16) & 1u);   // RNE
  return (unsigned short)(r >> 16);
}
__device__ inline float fast_tanh(float x){
  float e = __expf(2.0f*x);
  return 1.0f - 2.0f/(e + 1.0f);
}
__device__ inline void gl16(const void* g, void* l){
  __builtin_amdgcn_global_load_lds((const __attribute__((address_space(1))) u32*)g,
                                   (__attribute__((address_space(3))) u32*)l, 16, 0, 0);
}

// ---------- W (H x A fp32, row-major) -> Wt (A x H bf16) ----------
__global__ __launch_bounds__(256) void k_transpose(
    const float* __restrict__ Wh, const float* __restrict__ Wimg,
    unsigned short* __restrict__ WtH, unsigned short* __restrict__ WtImg){
  const float* src = blockIdx.y ? Wimg : Wh;
  unsigned short* dst = blockIdx.y ? WtImg : WtH;
  int tk = (blockIdx.x & 31) * 32;
  int ta = (blockIdx.x >> 5) * 32;
  __shared__ unsigned short tile[32][33];
  int t = threadIdx.x;
  int r = t >> 3, c4 = t & 7;
  float4 vv = *(const float4*)(src + (size_t)(tk + r)*A_ + ta + c4*4);
  tile[c4*4+0][r] = f2bf(vv.x);
  tile[c4*4+1][r] = f2bf(vv.y);
  tile[c4*4+2][r] = f2bf(vv.z);
  tile[c4*4+3][r] = f2bf(vv.w);
  __syncthreads();
  ushort4 o;
  o.x = tile[r][c4*4+0]; o.y = tile[r][c4*4+1];
  o.z = tile[r][c4*4+2]; o.w = tile[r][c4*4+3];
  *(ushort4*)(dst + (size_t)(ta + r)*H_ + tk + c4*4) = o;
}

// ================= h_proj GEMM core (round-1 proven, small) =================
#define BK 64
#define LDK 72

__device__ inline void gemm_tile(const float* __restrict__ Asrc,
                                 const unsigned short* __restrict__ Wt,
                                 int m0, int a0, f32x4 acc[4][4],
                                 unsigned short (*sA)[LDK], unsigned short (*sB)[LDK]){
  const int t = threadIdx.x;
  const int l = t & 63, w = t >> 6;
  const int wr = w >> 1, wc = w & 1;
  const int g = l >> 4, c = l & 15;
  #pragma unroll
  for (int m=0;m<4;m++)
    #pragma unroll
    for (int n=0;n<4;n++)
      acc[m][n] = f32x4{0.f,0.f,0.f,0.f};

  for (int k0 = 0; k0 < H_; k0 += BK){
    #pragma unroll
    for (int i=0;i<8;i++){
      int f = i*256 + t;
      int row = f >> 4, c4 = f & 15;
      float4 vv = *(const float4*)(Asrc + (size_t)(m0+row)*H_ + k0 + c4*4);
      ushort4 h; h.x=f2bf(vv.x); h.y=f2bf(vv.y); h.z=f2bf(vv.z); h.w=f2bf(vv.w);
      *(ushort4*)&sA[row][c4*4] = h;
    }
    #pragma unroll
    for (int i=0;i<8;i++){
      int f = i*256 + t;
      int row = f >> 4, c4 = f & 15;
      *(ushort4*)&sB[row][c4*4] = *(const ushort4*)(Wt + (size_t)(a0+row)*H_ + k0 + c4*4);
    }
    __syncthreads();
    #pragma unroll
    for (int kk=0; kk<BK; kk+=32){
      short8 aF[4], bF[4];
      #pragma unroll
      for (int m=0;m<4;m++) aF[m] = *(const short8*)&sA[wr*64 + m*16 + c][kk + g*8];
      #pragma unroll
      for (int n=0;n<4;n++) bF[n] = *(const short8*)&sB[wc*64 + n*16 + c][kk + g*8];
      #pragma unroll
      for (int m=0;m<4;m++)
        #pragma unroll
        for (int n=0;n<4;n++)
          acc[m][n] = __builtin_amdgcn_mfma_f32_16x16x32_bf16(aF[m], bF[n], acc[m][n], 0, 0, 0);
    }
    __syncthreads();
  }
}

// ---------- h_proj = hidden @ W_h + b_h ----------
__global__ __launch_bounds__(256) void k_hproj(
    const float* __restrict__ hidden, const unsigned short* __restrict__ WtH,
    const float* __restrict__ b_h, float* __restrict__ hproj){
  __shared__ __align__(16) unsigned short sA[128][LDK];
  __shared__ __align__(16) unsigned short sB[128][LDK];
  f32x4 acc[4][4];
  int m0 = blockIdx.x * 128, a0 = blockIdx.y * 128;
  gemm_tile(hidden, WtH, m0, a0, acc, sA, sB);
  const int l = threadIdx.x & 63, w = threadIdx.x >> 6;
  const int wr = w >> 1, wc = w & 1, g = l >> 4, c = l & 15;
  #pragma unroll
  for (int n=0;n<4;n++){
    int col = a0 + wc*64 + n*16 + c;
    float bh = b_h[col];
    #pragma unroll
    for (int m=0;m<4;m++)
      #pragma unroll
      for (int r=0;r<4;r++){
        int rowg = m0 + wr*64 + m*16 + g*4 + r;
        hproj[(size_t)rowg*A_ + col] = acc[m][n][r] + bh;
      }
  }
}

// ============ scores GEMM: fp32 A staged via global_load_lds, cvt_pk at frag load ============
// BM=128, BN=256, BK=64. LDS per buf: A fp32 [128][64]=32KB + B bf16 [256][64]=32KB; dbuf=128KB.
// XOR swizzle byte ^= ((row&7)<<4) on 16B granules, pre-applied on the GLOBAL source so
// global_load_lds' linear write lands swizzled data; reads XOR with the same mask (rule 21).
// 2-barrier K-loop with counted vmcnt(8) (round-4 proven): stage(t+1) -> vmcnt(8)
// [tile t's 8 loads fully landed, tile t+1's 8 in flight] -> barrier -> compute(t) -> barrier.
__global__ __launch_bounds__(512, 2) void k_scores_d(
    const float* __restrict__ img, const unsigned short* __restrict__ Wt,
    const float* __restrict__ hproj, const float* __restrict__ b_img,
    const float* __restrict__ cov, const float* __restrict__ Wcov,
    const float* __restrict__ v, float* __restrict__ scoresP){
  __shared__ __align__(16) char lds[131072];
  __shared__ float sS[128];
  __shared__ float sH[4][256];

  const int t = threadIdx.x;
  const int l = t & 63, w = t >> 6;       // 8 waves
  const int wr = w >> 2, wc = w & 3;      // 2 (M) x 4 (N); per-wave 64x64 out
  const int g = l >> 4, c = l & 15;
  const int cm = (c & 7) << 4;            // read-side XOR swizzle (row&7 == c&7)

  // bijective XCD-chunked swizzle; bid and bid+8 (same XCD, adjacent) form the
  // (a0=0, a0=256) pair over one A-panel -> L2/L3 absorbs the second A read.
  const int nwg = (M_/128)*(A_/256);      // 1568, %8==0
  int bid = blockIdx.x;
  int wg = (bid & 7)*(nwg/8) + (bid >> 3);
  const int m0 = (wg >> 1) * 128;
  const int a0 = (wg & 1) * 256;

  // staging lane geometry
  const int arow_l = l >> 4;              // A: 4 rows/chunk, 16 granules/row (256B)
  const int aslot  = l & 15;
  const int brow_l = l >> 3;              // B: 8 rows/chunk, 8 granules/row (128B)
  const int bslot  = l & 7;

  f32x4 acc[4][4] = {};

  auto stage = [&](int bn, int k0){
    #pragma unroll
    for (int q=0;q<4;q++){
      int arow = w*16 + q*4 + arow_l;
      int abo  = (aslot*16) ^ ((arow & 7) << 4);      // bytes within 256B row
      gl16(img + (size_t)(m0 + arow)*H_ + k0 + (abo >> 2),
           lds + bn*65536 + w*4096 + q*1024);
      int brow = w*32 + q*8 + brow_l;
      int bbo  = (bslot*16) ^ ((brow & 7) << 4);      // bytes within 128B row
      gl16(Wt + (size_t)(a0 + brow)*H_ + k0 + (bbo >> 1),
           lds + bn*65536 + 32768 + w*4096 + q*1024);
    }
  };

  auto compute = [&](int tt){
    const int cur = (tt & 1) << 16;
    const char* Ab = lds + cur;
    const char* Bb = lds + cur + 32768;
    #pragma unroll
    for (int k2=0;k2<2;k2++){
      short8 bF[4], aF[4];
      #pragma unroll
      for (int n=0;n<4;n++)
        bF[n] = *(const short8*)(Bb + (wc*64 + n*16 + c)*128 + ((k2*64 + g*16) ^ cm));
      #pragma unroll
      for (int m=0;m<4;m++){
        const char* ap = Ab + (wr*64 + m*16 + c)*256;
        const int bo = k2*128 + g*32;
        f32x4 lo = *(const f32x4*)(ap + (bo ^ cm));
        f32x4 hi = *(const f32x4*)(ap + ((bo+16) ^ cm));
        union { short8 s; u32 u[4]; } pk;
        asm("v_cvt_pk_bf16_f32 %0, %1, %2" : "=v"(pk.u[0]) : "v"(lo[0]), "v"(lo[1]));
        asm("v_cvt_pk_bf16_f32 %0, %1, %2" : "=v"(pk.u[1]) : "v"(lo[2]), "v"(lo[3]));
        asm("v_cvt_pk_bf16_f32 %0, %1, %2" : "=v"(pk.u[2]) : "v"(hi[0]), "v"(hi[1]));
        asm("v_cvt_pk_bf16_f32 %0, %1, %2" : "=v"(pk.u[3]) : "v"(hi[2]), "v"(hi[3]));
        aF[m] = pk.s;
      }
      __builtin_amdgcn_s_setprio(1);
      #pragma unroll
      for (int m=0;m<4;m++)
        #pragma unroll
        for (int n=0;n<4;n++)
          acc[m][n] = __builtin_amdgcn_mfma_f32_16x16x32_bf16(aF[m], bF[n], acc[m][n], 0, 0, 0);
      __builtin_amdgcn_s_setprio(0);
    }
  };

  stage(0, 0);
  for (int tt=0; tt<16; ++tt){
    if (tt < 15){
      stage((tt+1)&1, (tt+1)*64);
      asm volatile("s_waitcnt vmcnt(8)" ::: "memory");  // tile-tt's 8 landed
    } else {
      asm volatile("s_waitcnt vmcnt(0)" ::: "memory");
    }
    asm volatile("s_barrier" ::: "memory");
    compute(tt);
    asm volatile("s_barrier" ::: "memory");
  }

  // ---------------- epilogue: tanh + v-dot + row-reduce ----------------
  const int bFirst = m0 / N_;
  const int nB = (m0 + 127)/N_ - bFirst + 1;   // <= 4
  if (t < 128) sS[t] = 0.f;
  for (int idx = t; idx < nB*256; idx += 512){
    int bb = idx >> 8, a = idx & 255;
    sH[bb][a] = hproj[(size_t)(bFirst + bb)*A_ + a0 + a];
  }
  __syncthreads();

  float vv[4], bi[4], wcv[4];
  #pragma unroll
  for (int n=0;n<4;n++){
    int colg = a0 + wc*64 + n*16 + c;
    vv[n] = v[colg]; bi[n] = b_img[colg]; wcv[n] = Wcov[colg];
  }
  #pragma unroll
  for (int m=0;m<4;m++){
    #pragma unroll
    for (int r=0;r<4;r++){
      int rowl = wr*64 + m*16 + g*4 + r;
      int bb = (m0 + rowl) / N_ - bFirst;
      float cv = cov[m0 + rowl];
      float s = 0.f;
      #pragma unroll
      for (int n=0;n<4;n++){
        float x = acc[m][n][r] + sH[bb][wc*64 + n*16 + c] + bi[n] + cv*wcv[n];
        s += fast_tanh(x) * vv[n];
      }
      s += __shfl_xor(s, 1, 16);
      s += __shfl_xor(s, 2, 16);
      s += __shfl_xor(s, 4, 16);
      s += __shfl_xor(s, 8, 16);
      if (c == 0) atomicAdd(&sS[rowl], s);
    }
  }
  __syncthreads();
  if (t < 128) scoresP[(size_t)(a0 >> 8)*M_ + m0 + t] = sS[t];
}

// ---------- softmax (2-slab scores) + context from fp32 img ----------
__global__ __launch_bounds__(256) void k_ctx2(
    const float* __restrict__ img, const float* __restrict__ scoresP,
    float* __restrict__ outCtx, float* __restrict__ outAlpha){
  int b = blockIdx.x;
  __shared__ float sAl[N_];
  int t = threadIdx.x;
  if (t < 64){
    float s = -1e30f;
    if (t < N_){
      size_t rg = (size_t)b*N_ + t;
      s = scoresP[rg] + scoresP[(size_t)M_ + rg];
    }
    float m = s;
    #pragma unroll
    for (int off=32; off>=1; off>>=1) m = fmaxf(m, __shfl_xor(m, off));
    float e = (t < N_) ? __expf(s - m) : 0.f;
    float sum = e;
    #pragma unroll
    for (int off=32; off>=1; off>>=1) sum += __shfl_xor(sum, off);
    float al = e / sum;
    if (t < N_){ sAl[t] = al; outAlpha[(size_t)b*N_ + t] = al; }
  }
  __syncthreads();
  const float4* ib = (const float4*)(img + (size_t)b*N_*H_);
  float4 acc = {0.f,0.f,0.f,0.f};
  #pragma unroll 7
  for (int n=0;n<N_;n++){
    float al = sAl[n];
    float4 x = ib[n*(H_/4) + t];
    acc.x += al*x.x; acc.y += al*x.y; acc.z += al*x.z; acc.w += al*x.w;
  }
  *(float4*)(outCtx + (size_t)b*H_ + t*4) = acc;
}

extern "C" void kernel_launch(void* const* d_in, const int* in_sizes, int n_in,
                              void* d_out, int out_size, void* d_ws, size_t ws_size,
                              hipStream_t stream){
  const float* hidden = (const float*)d_in[0];
  const float* img    = (const float*)d_in[1];
  const float* cov    = (const float*)d_in[2];
  const float* W_h    = (const float*)d_in[3];
  const float* b_h    = (const float*)d_in[4];
  const float* W_img  = (const float*)d_in[5];
  const float* b_img  = (const float*)d_in[6];
  const float* W_cov  = (const float*)d_in[7];
  const float* v      = (const float*)d_in[8];

  char* ws = (char*)d_ws;
  unsigned short* WtH   = (unsigned short*)ws;               // 1 MB
  unsigned short* WtImg = (unsigned short*)(ws + (1u<<20));  // 1 MB
  float* hproj   = (float*)(ws + (2u<<20));                  // 4 MB
  float* scoresP = (float*)(ws + (6u<<20));                  // 2 slabs, 0.8 MB

  float* outCtx   = (float*)d_out;
  float* outAlpha = outCtx + (size_t)B_*H_;

  k_transpose<<<dim3(512, 2), 256, 0, stream>>>(W_h, W_img, WtH, WtImg);
  k_hproj<<<dim3(B_/128, A_/128), 256, 0, stream>>>(hidden, WtH, b_h, hproj);
  k_scores_d<<<(M_/128)*(A_/256), 512, 0, stream>>>(img, WtImg, hproj, b_img, cov, W_cov, v, scoresP);
  k_ctx2<<<B_, 256, 0, stream>>>(img, scoresP, outCtx, outAlpha);
}